// Round 12
// baseline (94.701 us; speedup 1.0000x reference)
//
#include <hip/hip_runtime.h>
#include <math.h>

#define H 2048
#define E 64
#define TAU 1e-6f     // p-gap guard (proven r3/5-r11): logit err ~2.5e-7 -> p err ~4e-9 << TAU

// ---- MFMA path geometry ----
#define MT 16         // rows per block -> grid 1024

// ---- round-5 fallback geometry ----
#define RB 16
#define CB 512
#define NCH (H / CB)
#define PITCH 516

// d_ws layout
#define WHI_OFF 65792u                     // after flags (65540 B), 256-aligned
#define WFRAG_BYTES 262144u                // 64kc * 4n * 64lane * 8 bf16 * 2B
#define WLO_OFF (WHI_OFF + WFRAG_BYTES)
#define WS_NEEDED ((size_t)(WLO_OFF + WFRAG_BYTES))   // 590080

typedef __attribute__((ext_vector_type(8))) short short8;
typedef __attribute__((ext_vector_type(4))) float f32x4;

__device__ __forceinline__ unsigned short bf16_rne(float f) {
    unsigned u = __float_as_uint(f);
    unsigned r = u + 0x7fffu + ((u >> 16) & 1u);
    return (unsigned short)(r >> 16);
}

// ============ kernel P: W' = pds*W (f64), split into bf16 hi/lo B-fragments ============
// frag elem (kc,n,lane,j) = W'[kc*32 + (lane>>4)*8 + j][n*16 + (lane&15)]
__global__ __launch_bounds__(64)
void prep_w(const float* __restrict__ Wm, const float* __restrict__ pds,
            int* __restrict__ flags,
            unsigned short* __restrict__ whi, unsigned short* __restrict__ wlo)
{
    const int fb   = blockIdx.x;        // 0..255 = kc*4 + n
    const int lane = threadIdx.x;       // 0..63
    if (fb == 0 && lane == 0) flags[0] = 0;
    const int kc  = fb >> 2;
    const int n   = fb & 3;
    const int r0  = kc * 32 + (lane >> 4) * 8;
    const int col = n * 16 + (lane & 15);

    short8 hv, lv;
#pragma unroll
    for (int j = 0; j < 8; ++j) {
        const int r = r0 + j;
        const double w = (double)pds[r] * (double)Wm[r * E + col];  // exact in f64
        const unsigned short hb = bf16_rne((float)w);
        const double hd = (double)__uint_as_float((unsigned)hb << 16);
        const unsigned short lb = bf16_rne((float)(w - hd));
        hv[j] = (short)hb;
        lv[j] = (short)lb;
    }
    const size_t off = ((size_t)fb * 64 + lane) * 8;
    *(short8*)(whi + off) = hv;
    *(short8*)(wlo + off) = lv;
}

// ============ kernel M: contiguous-stream MFMA router ============
// Theory: r5-r11 all read x as ~64K interleaved 128-512B chunk-streams at 8KB
// row stride -> ~1.7 TB/s effective (vs 7.2 TB/s for the harness's LINEAR
// fill). Here phase A streams each half-row as ONE contiguous 4KB burst per
// instruction (256 thr x 16B), converts f32->bf16 hi/lo in-register, stores
// into a 64KB LDS tile (XOR-swizzled 16B units). Phase B runs the verified
// frag-MFMA on LDS. 2 blocks/CU -> A(mem) overlaps B(compute) across blocks.
__global__ __launch_bounds__(256, 2)
void router_ct(const float* __restrict__ x,
               const unsigned short* __restrict__ whi,
               const unsigned short* __restrict__ wlo,
               float* __restrict__ out,
               int* __restrict__ flags)
{
    // [plane hi/lo][row][1024 k] bf16 = 64 KB; dead after K-loop -> front
    // 16 KB aliased as lbuf[4 waves][16 rows][64 experts] f32.
    __shared__ __align__(16) unsigned short xb[2][MT][1024];
    __shared__ float ssbuf[64];
    __shared__ float sfac[16];

    const int t    = threadIdx.x;
    const int wid  = t >> 6;
    const int lane = t & 63;
    const int lsub = lane & 15;         // A-frag row
    const int lgrp = lane >> 4;         // A-frag k-group
    const int row0 = blockIdx.x * MT;

    const int wunit = t >> 1;           // phase-A 16B unit (2 threads/unit)
    const int wsub  = (t & 1) * 4;      // ushort sub-offset within unit

    f32x4 acc[4] = {{0.f,0.f,0.f,0.f},{0.f,0.f,0.f,0.f},
                    {0.f,0.f,0.f,0.f},{0.f,0.f,0.f,0.f}};
    float sq = 0.0f;

#pragma unroll
    for (int h = 0; h < 2; ++h) {
        // ---- phase A: stream 16 half-rows, each a contiguous 4KB burst ----
#pragma unroll
        for (int b2 = 0; b2 < 2; ++b2) {
            float4 xv[8];                         // 8 bursts in flight (32 KB/block)
#pragma unroll
            for (int j = 0; j < 8; ++j) {
                const int i = b2 * 8 + j;
                xv[j] = *(const float4*)(x + (size_t)(row0 + i) * H + h * 1024 + t * 4);
            }
#pragma unroll
            for (int j = 0; j < 8; ++j) {
                const int i = b2 * 8 + j;
                const float f[4] = { xv[j].x, xv[j].y, xv[j].z, xv[j].w };
                unsigned hu[4], lu[4];
#pragma unroll
                for (int e = 0; e < 4; ++e) {
                    const unsigned short hb = bf16_rne(f[e]);
                    const unsigned short lb = bf16_rne(f[e] - __uint_as_float((unsigned)hb << 16));
                    hu[e] = hb; lu[e] = lb;
                }
                const int uph = wunit ^ (i & 7);          // write-side swizzle
                const int idx = uph * 8 + wsub;           // ushort index in row
                *(uint2*)(&xb[0][i][idx]) = make_uint2(hu[0] | (hu[1] << 16), hu[2] | (hu[3] << 16));
                *(uint2*)(&xb[1][i][idx]) = make_uint2(lu[0] | (lu[1] << 16), lu[2] | (lu[3] << 16));
            }
        }
        __syncthreads();

        // ---- phase B: wave wid covers kc in [h*32 + wid*8, +8), 2 groups of 4 ----
#pragma unroll
        for (int g = 0; g < 2; ++g) {
            // batch W' fragments (32 coalesced 1KB loads -> one L2 latency)
            short8 WH[16], WL[16];
#pragma unroll
            for (int kl = 0; kl < 4; ++kl) {
                const size_t kc = (size_t)(h * 32 + wid * 8 + g * 4 + kl);
                const unsigned short* ph = whi + (kc * 256 + lane) * 8;
                const unsigned short* pl = wlo + (kc * 256 + lane) * 8;
#pragma unroll
                for (int n = 0; n < 4; ++n) {
                    WH[kl * 4 + n] = *(const short8*)(ph + n * 512);
                    WL[kl * 4 + n] = *(const short8*)(pl + n * 512);
                }
            }
            __builtin_amdgcn_sched_barrier(0);

            // A-frags from LDS (read-side swizzle matches write-side)
            short8 AH[4], AL[4];
#pragma unroll
            for (int kl = 0; kl < 4; ++kl) {
                const int v   = wid * 32 + (g * 4 + kl) * 4 + lgrp;  // 16B unit in row
                const int idx = lsub * 1024 + (v ^ (lsub & 7)) * 8;
                AH[kl] = *(const short8*)(&xb[0][0][idx]);
                AL[kl] = *(const short8*)(&xb[1][0][idx]);
            }
            __builtin_amdgcn_sched_barrier(0);

#pragma unroll
            for (int kl = 0; kl < 4; ++kl) {
                // sum(x^2) from hi+lo reconstruction (rel err ~3e-8, scale-only)
#pragma unroll
                for (int e = 0; e < 8; ++e) {
                    const float hf = __uint_as_float(((unsigned)(unsigned short)AH[kl][e]) << 16);
                    const float lf = __uint_as_float(((unsigned)(unsigned short)AL[kl][e]) << 16);
                    const float xr = hf + lf;
                    sq = fmaf(xr, xr, sq);
                }
#pragma unroll
                for (int n = 0; n < 4; ++n) {
                    acc[n] = __builtin_amdgcn_mfma_f32_16x16x32_bf16(AH[kl], WH[kl * 4 + n], acc[n], 0, 0, 0);
                    acc[n] = __builtin_amdgcn_mfma_f32_16x16x32_bf16(AH[kl], WL[kl * 4 + n], acc[n], 0, 0, 0);
                    acc[n] = __builtin_amdgcn_mfma_f32_16x16x32_bf16(AL[kl], WH[kl * 4 + n], acc[n], 0, 0, 0);
                }
            }
        }
        __syncthreads();   // waves done reading xb before next A overwrites / alias
    }

    // ---- per-wave partial logits (aliases xb; C frag col=lane&15, row=(lane>>4)*4+q) ----
    float* lbuf = (float*)xb;             // [wave][16 rows][64 experts]
#pragma unroll
    for (int n = 0; n < 4; ++n)
#pragma unroll
        for (int q = 0; q < 4; ++q)
            lbuf[wid * 1024 + (lgrp * 4 + q) * E + n * 16 + lsub] = acc[n][q];

    // sum(x^2): fold 4 k-group lanes per row, then across waves
    sq += __shfl_xor(sq, 16);
    sq += __shfl_xor(sq, 32);
    if (lane < 16) ssbuf[wid * 16 + lane] = sq;
    __syncthreads();

    if (t < 16) {
        const float tot = ssbuf[t] + ssbuf[16 + t] + ssbuf[32 + t] + ssbuf[48 + t];
        sfac[t] = rsqrtf(tot * (1.0f / (float)H) + 1e-6f) * 0.022097086912079608f;
    }
    __syncthreads();

    // ---- epilogue (verified r5-r11): wave wid owns rows wid*4..+3; lane=expert ----
#pragma unroll
    for (int rr = 0; rr < 4; ++rr) {
        const int r = wid * 4 + rr;
        const float L = (lbuf[r * E + lane]        + lbuf[1024 + r * E + lane]
                       + lbuf[2048 + r * E + lane] + lbuf[3072 + r * E + lane]) * sfac[r];

        float m = L;
#pragma unroll
        for (int off = 32; off >= 1; off >>= 1)
            m = fmaxf(m, __shfl_xor(m, off));
        const float ev = expf(L - m);
        float S = ev;
#pragma unroll
        for (int off = 32; off >= 1; off >>= 1)
            S += __shfl_xor(S, off);
        const float p = ev / S;

        float v1 = p; int i1 = lane;
#pragma unroll
        for (int off = 32; off >= 1; off >>= 1) {
            const float ov = __shfl_xor(v1, off);
            const int   oi = __shfl_xor(i1, off);
            if (ov > v1 || (ov == v1 && oi < i1)) { v1 = ov; i1 = oi; }
        }
        float v2 = (lane == i1) ? -1.0f : p; int i2 = lane;
#pragma unroll
        for (int off = 32; off >= 1; off >>= 1) {
            const float ov = __shfl_xor(v2, off);
            const int   oi = __shfl_xor(i2, off);
            if (ov > v2 || (ov == v2 && oi < i2)) { v2 = ov; i2 = oi; }
        }
        float v3 = (lane == i1 || lane == i2) ? -1.0f : p;
#pragma unroll
        for (int off = 32; off >= 1; off >>= 1)
            v3 = fmaxf(v3, __shfl_xor(v3, off));

        if (lane == 0 && (v2 - v3) < TAU) {
            const int k = atomicAdd(flags, 1);
            flags[1 + k] = row0 + r;
        }

        const float denom = fmaxf(v1 + v2, 1e-9f);
        const float wA = v1 / denom;
        const float wB = v2 / denom;
        const float o  = (lane == i1) ? wA : ((lane == i2) ? wB : 0.0f);
        out[(size_t)(row0 + r) * E + lane] = o;
    }
}

// ============ kernel F: exact-f64 repair of flagged rows (round-3 proven) ============
__global__ __launch_bounds__(256)
void router_fix(const float* __restrict__ x,
                const float* __restrict__ pds,
                const float* __restrict__ Wm,
                float* __restrict__ out,
                const int* __restrict__ flags)
{
    __shared__ double yd[H];
    __shared__ double parts[4 * E];
    __shared__ double ss[256];

    const int t = threadIdx.x;
    const int count = flags[0];

    for (int j = blockIdx.x; j < count; j += gridDim.x) {
        const int r = flags[1 + j];
        const float* xr = x + (size_t)r * H;

        double s = 0.0;
#pragma unroll
        for (int i = 0; i < 8; ++i) {
            const int h = t * 8 + i;
            const double xv = (double)xr[h];
            s += xv * xv;
            yd[h] = xv * (double)pds[h];
        }
        ss[t] = s;
        __syncthreads();

        const int ex = t & 63;
        const int sl = t >> 6;
        const float* wp = Wm + (size_t)(sl * 512) * E + ex;
        double acc = 0.0;
#pragma unroll 8
        for (int h = 0; h < 512; ++h)
            acc = fma(yd[sl * 512 + h], (double)wp[(size_t)h * E], acc);
        parts[sl * E + ex] = acc;
        __syncthreads();

        if (t < 64) {
            const int lane = t;
            double tot = ss[lane * 4] + ss[lane * 4 + 1] + ss[lane * 4 + 2] + ss[lane * 4 + 3];
#pragma unroll
            for (int off = 32; off >= 1; off >>= 1)
                tot += __shfl_xor(tot, off);
            const double sf = (1.0 / sqrt(tot * (1.0 / (double)H) + 1e-6)) * 0.022097086912079608;

            const double Ld = parts[0 * E + lane] + parts[1 * E + lane]
                            + parts[2 * E + lane] + parts[3 * E + lane];
            const float L = (float)(Ld * sf);

            float m = L;
#pragma unroll
            for (int off = 32; off >= 1; off >>= 1)
                m = fmaxf(m, __shfl_xor(m, off));
            const float ev = (float)exp((double)(L - m));
            float S = ev;
#pragma unroll
            for (int off = 32; off >= 1; off >>= 1)
                S += __shfl_xor(S, off);
            const float p = ev / S;

            float v1 = p; int i1 = lane;
#pragma unroll
            for (int off = 32; off >= 1; off >>= 1) {
                const float ov = __shfl_xor(v1, off);
                const int   oi = __shfl_xor(i1, off);
                if (ov > v1 || (ov == v1 && oi < i1)) { v1 = ov; i1 = oi; }
            }
            float v2 = (lane == i1) ? -1.0f : p; int i2 = lane;
#pragma unroll
            for (int off = 32; off >= 1; off >>= 1) {
                const float ov = __shfl_xor(v2, off);
                const int   oi = __shfl_xor(i2, off);
                if (ov > v2 || (ov == v2 && oi < i2)) { v2 = ov; i2 = oi; }
            }

            const float denom = fmaxf(v1 + v2, 1e-9f);
            const float wA = v1 / denom;
            const float wB = v2 / denom;
            const float o  = (lane == i1) ? wA : ((lane == i2) ? wB : 0.0f);
            out[(size_t)r * E + lane] = o;
        }
        __syncthreads();
    }
}

// ============ round-5 fallback (verified) in case ws_size is small ============
__global__ void zero_cnt(int* __restrict__ flags) {
    if (threadIdx.x == 0 && blockIdx.x == 0) flags[0] = 0;
}

__global__ __launch_bounds__(256)
void router_f32(const float* __restrict__ x,
                const float* __restrict__ pds,
                const float* __restrict__ Wm,
                float* __restrict__ out,
                int* __restrict__ flags)
{
    __shared__ __align__(16) float yb[RB * PITCH];
    __shared__ float ssbuf[256];
    __shared__ float sfac[RB];

    const int t    = threadIdx.x;
    const int wv_i = t >> 6;
    const int lane = t & 63;
    const int g    = lane >> 4;
    const int e0   = (lane & 15) << 2;

    const int row0 = blockIdx.x * RB;
    const int srow = t >> 4;
    const int sseg = t & 15;

    const float* xrow = x + (size_t)(row0 + srow) * H;

    float acc[4][4];
#pragma unroll
    for (int a = 0; a < 4; ++a)
#pragma unroll
        for (int b = 0; b < 4; ++b) acc[a][b] = 0.0f;

    float sumsq = 0.0f;
    float4 xv[8];
#pragma unroll
    for (int i = 0; i < 8; ++i)
        xv[i] = *(const float4*)(xrow + sseg * 4 + i * 64);

    for (int c = 0; c < NCH; ++c) {
        const float* pbase = pds + c * CB;
#pragma unroll
        for (int i = 0; i < 8; ++i) {
            const int hl = sseg * 4 + i * 64;
            const float4 a4 = xv[i];
            const float4 p4 = *(const float4*)(pbase + hl);
            sumsq += a4.x * a4.x + a4.y * a4.y + a4.z * a4.z + a4.w * a4.w;
            float4 y4;
            y4.x = a4.x * p4.x; y4.y = a4.y * p4.y;
            y4.z = a4.z * p4.z; y4.w = a4.w * p4.w;
            *(float4*)(&yb[srow * PITCH + hl]) = y4;
        }
        __syncthreads();

        if (c + 1 < NCH) {
            const int h0n = (c + 1) * CB;
#pragma unroll
            for (int i = 0; i < 8; ++i)
                xv[i] = *(const float4*)(xrow + h0n + sseg * 4 + i * 64);
        }

        const int hb = wv_i * 128;
        const float* wbase = Wm + (size_t)(c * CB) * E + e0;
#pragma unroll 2
        for (int s = 0; s < 32; ++s) {
            const int hh = hb + s * 4;
            const float4 w0 = *(const float4*)(wbase + (size_t)(hh + 0) * E);
            const float4 w1 = *(const float4*)(wbase + (size_t)(hh + 1) * E);
            const float4 w2 = *(const float4*)(wbase + (size_t)(hh + 2) * E);
            const float4 w3 = *(const float4*)(wbase + (size_t)(hh + 3) * E);
#pragma unroll
            for (int rr = 0; rr < 4; ++rr) {
                const float4 y4 = *(const float4*)(&yb[(4 * rr + g) * PITCH + hh]);
                acc[rr][0] = fmaf(y4.w, w3.x, fmaf(y4.z, w2.x, fmaf(y4.y, w1.x, fmaf(y4.x, w0.x, acc[rr][0]))));
                acc[rr][1] = fmaf(y4.w, w3.y, fmaf(y4.z, w2.y, fmaf(y4.y, w1.y, fmaf(y4.x, w0.y, acc[rr][1]))));
                acc[rr][2] = fmaf(y4.w, w3.z, fmaf(y4.z, w2.z, fmaf(y4.y, w1.z, fmaf(y4.x, w0.z, acc[rr][2]))));
                acc[rr][3] = fmaf(y4.w, w3.w, fmaf(y4.z, w2.w, fmaf(y4.y, w1.w, fmaf(y4.x, w0.w, acc[rr][3]))));
            }
        }
        __syncthreads();
    }

    ssbuf[t] = sumsq;
    __syncthreads();
    if (t < RB) {
        float tot = 0.0f;
#pragma unroll
        for (int i = 0; i < 16; ++i) tot += ssbuf[t * 16 + i];
        sfac[t] = rsqrtf(tot * (1.0f / (float)H) + 1e-6f) * 0.022097086912079608f;
    }

#pragma unroll
    for (int rr = 0; rr < 4; ++rr) {
        const int r = 4 * rr + g;
        *(float4*)(&yb[((wv_i * RB) + r) * E + e0]) =
            make_float4(acc[rr][0], acc[rr][1], acc[rr][2], acc[rr][3]);
    }
    __syncthreads();

#pragma unroll
    for (int rr = 0; rr < 4; ++rr) {
        const int r = wv_i * 4 + rr;
        float L = yb[(0 * RB + r) * E + lane] + yb[(1 * RB + r) * E + lane]
                + yb[(2 * RB + r) * E + lane] + yb[(3 * RB + r) * E + lane];
        L *= sfac[r];

        float m = L;
#pragma unroll
        for (int off = 32; off >= 1; off >>= 1)
            m = fmaxf(m, __shfl_xor(m, off));
        const float ev = expf(L - m);
        float S = ev;
#pragma unroll
        for (int off = 32; off >= 1; off >>= 1)
            S += __shfl_xor(S, off);
        const float p = ev / S;

        float v1 = p; int i1 = lane;
#pragma unroll
        for (int off = 32; off >= 1; off >>= 1) {
            const float ov = __shfl_xor(v1, off);
            const int   oi = __shfl_xor(i1, off);
            if (ov > v1 || (ov == v1 && oi < i1)) { v1 = ov; i1 = oi; }
        }
        float v2 = (lane == i1) ? -1.0f : p; int i2 = lane;
#pragma unroll
        for (int off = 32; off >= 1; off >>= 1) {
            const float ov = __shfl_xor(v2, off);
            const int   oi = __shfl_xor(i2, off);
            if (ov > v2 || (ov == v2 && oi < i2)) { v2 = ov; i2 = oi; }
        }
        float v3 = (lane == i1 || lane == i2) ? -1.0f : p;
#pragma unroll
        for (int off = 32; off >= 1; off >>= 1)
            v3 = fmaxf(v3, __shfl_xor(v3, off));

        if (lane == 0 && (v2 - v3) < TAU) {
            const int k = atomicAdd(flags, 1);
            flags[1 + k] = row0 + r;
        }

        const float denom = fmaxf(v1 + v2, 1e-9f);
        const float wA = v1 / denom;
        const float wB = v2 / denom;
        const float o  = (lane == i1) ? wA : ((lane == i2) ? wB : 0.0f);
        out[(size_t)(row0 + r) * E + lane] = o;
    }
}

extern "C" void kernel_launch(void* const* d_in, const int* in_sizes, int n_in,
                              void* d_out, int out_size, void* d_ws, size_t ws_size,
                              hipStream_t stream) {
    const float* x   = (const float*)d_in[0];
    const float* pds = (const float*)d_in[1];
    const float* Wm  = (const float*)d_in[2];
    float* out = (float*)d_out;
    int* flags = (int*)d_ws;

    const int T = in_sizes[0] / H;   // 16384

    if (ws_size >= WS_NEEDED) {
        unsigned short* whi = (unsigned short*)((char*)d_ws + WHI_OFF);
        unsigned short* wlo = (unsigned short*)((char*)d_ws + WLO_OFF);
        hipLaunchKernelGGL(prep_w,     dim3(256),    dim3(64),  0, stream, Wm, pds, flags, whi, wlo);
        hipLaunchKernelGGL(router_ct,  dim3(T / MT), dim3(256), 0, stream, x, whi, wlo, out, flags);
        hipLaunchKernelGGL(router_fix, dim3(128),    dim3(256), 0, stream, x, pds, Wm, out, flags);
    } else {
        hipLaunchKernelGGL(zero_cnt,   dim3(1),      dim3(64),  0, stream, flags);
        hipLaunchKernelGGL(router_f32, dim3(T / RB), dim3(256), 0, stream, x, pds, Wm, out, flags);
        hipLaunchKernelGGL(router_fix, dim3(128),    dim3(256), 0, stream, x, pds, Wm, out, flags);
    }
}

// Round 13
// 83.202 us; speedup vs baseline: 1.1382x; 1.1382x over previous
//
#include <hip/hip_runtime.h>
#include <math.h>

#define H 2048
#define E 64
#define TAU 1e-6f     // p-gap guard (proven r3/5-r12): logit err ~2.5e-7 -> p err ~4e-9 << TAU

// ---- MFMA path geometry ----
#define MT 64         // rows per block -> grid 256 = 1 block/CU, 8 waves (2/SIMD)

// ---- round-5 fallback geometry ----
#define RB 16
#define CB 512
#define NCH (H / CB)
#define PITCH 516

// d_ws layout
#define WHI_OFF 65792u                     // after flags (65540 B), 256-aligned
#define WFRAG_BYTES 262144u                // 64kc * 4n * 64lane * 8 bf16 * 2B
#define WLO_OFF (WHI_OFF + WFRAG_BYTES)
#define WS_NEEDED ((size_t)(WLO_OFF + WFRAG_BYTES))   // 590080

typedef __attribute__((ext_vector_type(8))) short short8;
typedef __attribute__((ext_vector_type(4))) float f32x4;

__device__ __forceinline__ unsigned short bf16_rne(float f) {
    unsigned u = __float_as_uint(f);
    unsigned r = u + 0x7fffu + ((u >> 16) & 1u);
    return (unsigned short)(r >> 16);
}

// ============ kernel P: W' = pds*W (f64), split into bf16 hi/lo B-fragments ============
// frag elem (kc,n,lane,j) = W'[kc*32 + (lane>>4)*8 + j][n*16 + (lane&15)]
__global__ __launch_bounds__(64)
void prep_w(const float* __restrict__ Wm, const float* __restrict__ pds,
            int* __restrict__ flags,
            unsigned short* __restrict__ whi, unsigned short* __restrict__ wlo)
{
    const int fb   = blockIdx.x;        // 0..255 = kc*4 + n
    const int lane = threadIdx.x;       // 0..63
    if (fb == 0 && lane == 0) flags[0] = 0;
    const int kc  = fb >> 2;
    const int n   = fb & 3;
    const int r0  = kc * 32 + (lane >> 4) * 8;
    const int col = n * 16 + (lane & 15);

    short8 hv, lv;
#pragma unroll
    for (int j = 0; j < 8; ++j) {
        const int r = r0 + j;
        const double w = (double)pds[r] * (double)Wm[r * E + col];  // exact in f64
        const unsigned short hb = bf16_rne((float)w);
        const double hd = (double)__uint_as_float((unsigned)hb << 16);
        const unsigned short lb = bf16_rne((float)(w - hd));
        hv[j] = (short)hb;
        lv[j] = (short)lb;
    }
    const size_t off = ((size_t)fb * 64 + lane) * 8;
    *(short8*)(whi + off) = hv;
    *(short8*)(wlo + off) = lv;
}

// ============ kernel M: 4-tile W-amortized MFMA router ============
// TRAFFIC THEORY (r12 post-mortem): r5-r12 all moved ~640 MB (512 MB W-frag
// re-reads + 128 MB x) and all sat at the ~8-9 TB/s effective L2/L3 ceiling
// (640MB/72us). Here each wave holds ONE W-frag batch in registers and feeds
// FOUR 16-row A-tiles (64 rows/block) -> W traffic 512->128 MB, total ~260 MB.
// 512-thr blocks, wave w owns K-eighth (8 kc); grid 256 = 1 block/CU.
__global__ __launch_bounds__(512, 2)
void router_4t(const float* __restrict__ x,
               const unsigned short* __restrict__ whi,
               const unsigned short* __restrict__ wlo,
               float* __restrict__ out,
               int* __restrict__ flags)
{
    __shared__ float lbuf[4][MT * E];   // partial logits (two-stage merge), 64 KB
    __shared__ float ssbuf[8][MT];      // per-wave sum(x^2) partials
    __shared__ float sfac[MT];

    const int t    = threadIdx.x;
    const int wid  = t >> 6;            // 0..7, owns kc in [wid*8, wid*8+8)
    const int lane = t & 63;
    const int lsub = lane & 15;         // A-frag row-in-tile
    const int lgrp = lane >> 4;         // A-frag k-group
    const int row0 = blockIdx.x * MT;

    f32x4 acc[4][4];                    // [tile][n], 64 VGPR, static idx
#pragma unroll
    for (int a = 0; a < 4; ++a)
#pragma unroll
        for (int b = 0; b < 4; ++b) acc[a][b] = (f32x4){0.f, 0.f, 0.f, 0.f};
    float sq[4] = {0.f, 0.f, 0.f, 0.f};

    const float* xw = x + (size_t)row0 * H + wid * 256 + lgrp * 8;

    for (int kl = 0; kl < 8; ++kl) {
        const int kc = wid * 8 + kl;

        // W' fragment batch for this kc: 8 coalesced 1KB loads
        const unsigned short* ph = whi + ((size_t)kc * 256 + lane) * 8;
        const unsigned short* pl = wlo + ((size_t)kc * 256 + lane) * 8;
        short8 WH[4], WL[4];
#pragma unroll
        for (int n = 0; n < 4; ++n) {
            WH[n] = *(const short8*)(ph + n * 512);
            WL[n] = *(const short8*)(pl + n * 512);
        }

        // x frags for 4 row-tiles (lines fully consumed by the a0/a1 pair)
        float4 a0[4], a1[4];
#pragma unroll
        for (int tt = 0; tt < 4; ++tt) {
            const float* p = xw + (size_t)(tt * 16 + lsub) * H + kl * 32;
            a0[tt] = *(const float4*)p;
            a1[tt] = *(const float4*)(p + 4);
        }

        // convert to bf16 hi/lo and accumulate sum(x^2)
        short8 AH[4], AL[4];
#pragma unroll
        for (int tt = 0; tt < 4; ++tt) {
            const float f[8] = { a0[tt].x, a0[tt].y, a0[tt].z, a0[tt].w,
                                 a1[tt].x, a1[tt].y, a1[tt].z, a1[tt].w };
            sq[tt] += f[0]*f[0] + f[1]*f[1] + f[2]*f[2] + f[3]*f[3]
                    + f[4]*f[4] + f[5]*f[5] + f[6]*f[6] + f[7]*f[7];
#pragma unroll
            for (int e = 0; e < 8; ++e) {
                const unsigned short hb = bf16_rne(f[e]);
                const unsigned short lb = bf16_rne(f[e] - __uint_as_float((unsigned)hb << 16));
                AH[tt][e] = (short)hb;
                AL[tt][e] = (short)lb;
            }
        }

        // 4 tiles x 4 n x 3 terms: one W batch feeds 48 MFMAs
#pragma unroll
        for (int tt = 0; tt < 4; ++tt)
#pragma unroll
            for (int n = 0; n < 4; ++n) {
                acc[tt][n] = __builtin_amdgcn_mfma_f32_16x16x32_bf16(AH[tt], WH[n], acc[tt][n], 0, 0, 0);
                acc[tt][n] = __builtin_amdgcn_mfma_f32_16x16x32_bf16(AH[tt], WL[n], acc[tt][n], 0, 0, 0);
                acc[tt][n] = __builtin_amdgcn_mfma_f32_16x16x32_bf16(AL[tt], WH[n], acc[tt][n], 0, 0, 0);
            }
    }

    // ---- sum(x^2): fold lanes sharing lsub (lgrp axis), store per-wave ----
#pragma unroll
    for (int tt = 0; tt < 4; ++tt) {
        float s = sq[tt];
        s += __shfl_xor(s, 16);
        s += __shfl_xor(s, 32);
        if (lane < 16) ssbuf[wid][tt * 16 + lane] = s;
    }

    // ---- partial logits, two-stage merge (C frag: col=lane&15, row=(lane>>4)*4+q) ----
    if (wid < 4) {
#pragma unroll
        for (int tt = 0; tt < 4; ++tt)
#pragma unroll
            for (int n = 0; n < 4; ++n)
#pragma unroll
                for (int q = 0; q < 4; ++q)
                    lbuf[wid][(tt * 16 + lgrp * 4 + q) * E + n * 16 + lsub] = acc[tt][n][q];
    }
    __syncthreads();
    if (wid >= 4) {
#pragma unroll
        for (int tt = 0; tt < 4; ++tt)
#pragma unroll
            for (int n = 0; n < 4; ++n)
#pragma unroll
                for (int q = 0; q < 4; ++q)
                    lbuf[wid - 4][(tt * 16 + lgrp * 4 + q) * E + n * 16 + lsub] += acc[tt][n][q];
    }
    __syncthreads();

    if (t < MT) {
        const float tot = ssbuf[0][t] + ssbuf[1][t] + ssbuf[2][t] + ssbuf[3][t]
                        + ssbuf[4][t] + ssbuf[5][t] + ssbuf[6][t] + ssbuf[7][t];
        sfac[t] = rsqrtf(tot * (1.0f / (float)H) + 1e-6f) * 0.022097086912079608f;
    }
    __syncthreads();

    // ---- epilogue (verified r5-r12): wave wid owns rows wid*8..+7; lane=expert ----
#pragma unroll
    for (int rr = 0; rr < 8; ++rr) {
        const int r = wid * 8 + rr;
        const float L = (lbuf[0][r * E + lane] + lbuf[1][r * E + lane]
                       + lbuf[2][r * E + lane] + lbuf[3][r * E + lane]) * sfac[r];

        float m = L;
#pragma unroll
        for (int off = 32; off >= 1; off >>= 1)
            m = fmaxf(m, __shfl_xor(m, off));
        const float ev = expf(L - m);
        float S = ev;
#pragma unroll
        for (int off = 32; off >= 1; off >>= 1)
            S += __shfl_xor(S, off);
        const float p = ev / S;

        float v1 = p; int i1 = lane;
#pragma unroll
        for (int off = 32; off >= 1; off >>= 1) {
            const float ov = __shfl_xor(v1, off);
            const int   oi = __shfl_xor(i1, off);
            if (ov > v1 || (ov == v1 && oi < i1)) { v1 = ov; i1 = oi; }
        }
        float v2 = (lane == i1) ? -1.0f : p; int i2 = lane;
#pragma unroll
        for (int off = 32; off >= 1; off >>= 1) {
            const float ov = __shfl_xor(v2, off);
            const int   oi = __shfl_xor(i2, off);
            if (ov > v2 || (ov == v2 && oi < i2)) { v2 = ov; i2 = oi; }
        }
        float v3 = (lane == i1 || lane == i2) ? -1.0f : p;
#pragma unroll
        for (int off = 32; off >= 1; off >>= 1)
            v3 = fmaxf(v3, __shfl_xor(v3, off));

        if (lane == 0 && (v2 - v3) < TAU) {
            const int k = atomicAdd(flags, 1);
            flags[1 + k] = row0 + r;
        }

        const float denom = fmaxf(v1 + v2, 1e-9f);
        const float wA = v1 / denom;
        const float wB = v2 / denom;
        const float o  = (lane == i1) ? wA : ((lane == i2) ? wB : 0.0f);
        out[(size_t)(row0 + r) * E + lane] = o;
    }
}

// ============ kernel F: exact-f64 repair of flagged rows (round-3 proven) ============
__global__ __launch_bounds__(256)
void router_fix(const float* __restrict__ x,
                const float* __restrict__ pds,
                const float* __restrict__ Wm,
                float* __restrict__ out,
                const int* __restrict__ flags)
{
    __shared__ double yd[H];
    __shared__ double parts[4 * E];
    __shared__ double ss[256];

    const int t = threadIdx.x;
    const int count = flags[0];

    for (int j = blockIdx.x; j < count; j += gridDim.x) {
        const int r = flags[1 + j];
        const float* xr = x + (size_t)r * H;

        double s = 0.0;
#pragma unroll
        for (int i = 0; i < 8; ++i) {
            const int h = t * 8 + i;
            const double xv = (double)xr[h];
            s += xv * xv;
            yd[h] = xv * (double)pds[h];
        }
        ss[t] = s;
        __syncthreads();

        const int ex = t & 63;
        const int sl = t >> 6;
        const float* wp = Wm + (size_t)(sl * 512) * E + ex;
        double acc = 0.0;
#pragma unroll 8
        for (int h = 0; h < 512; ++h)
            acc = fma(yd[sl * 512 + h], (double)wp[(size_t)h * E], acc);
        parts[sl * E + ex] = acc;
        __syncthreads();

        if (t < 64) {
            const int lane = t;
            double tot = ss[lane * 4] + ss[lane * 4 + 1] + ss[lane * 4 + 2] + ss[lane * 4 + 3];
#pragma unroll
            for (int off = 32; off >= 1; off >>= 1)
                tot += __shfl_xor(tot, off);
            const double sf = (1.0 / sqrt(tot * (1.0 / (double)H) + 1e-6)) * 0.022097086912079608;

            const double Ld = parts[0 * E + lane] + parts[1 * E + lane]
                            + parts[2 * E + lane] + parts[3 * E + lane];
            const float L = (float)(Ld * sf);

            float m = L;
#pragma unroll
            for (int off = 32; off >= 1; off >>= 1)
                m = fmaxf(m, __shfl_xor(m, off));
            const float ev = (float)exp((double)(L - m));
            float S = ev;
#pragma unroll
            for (int off = 32; off >= 1; off >>= 1)
                S += __shfl_xor(S, off);
            const float p = ev / S;

            float v1 = p; int i1 = lane;
#pragma unroll
            for (int off = 32; off >= 1; off >>= 1) {
                const float ov = __shfl_xor(v1, off);
                const int   oi = __shfl_xor(i1, off);
                if (ov > v1 || (ov == v1 && oi < i1)) { v1 = ov; i1 = oi; }
            }
            float v2 = (lane == i1) ? -1.0f : p; int i2 = lane;
#pragma unroll
            for (int off = 32; off >= 1; off >>= 1) {
                const float ov = __shfl_xor(v2, off);
                const int   oi = __shfl_xor(i2, off);
                if (ov > v2 || (ov == v2 && oi < i2)) { v2 = ov; i2 = oi; }
            }

            const float denom = fmaxf(v1 + v2, 1e-9f);
            const float wA = v1 / denom;
            const float wB = v2 / denom;
            const float o  = (lane == i1) ? wA : ((lane == i2) ? wB : 0.0f);
            out[(size_t)r * E + lane] = o;
        }
        __syncthreads();
    }
}

// ============ round-5 fallback (verified) in case ws_size is small ============
__global__ void zero_cnt(int* __restrict__ flags) {
    if (threadIdx.x == 0 && blockIdx.x == 0) flags[0] = 0;
}

__global__ __launch_bounds__(256)
void router_f32(const float* __restrict__ x,
                const float* __restrict__ pds,
                const float* __restrict__ Wm,
                float* __restrict__ out,
                int* __restrict__ flags)
{
    __shared__ __align__(16) float yb[RB * PITCH];
    __shared__ float ssbuf[256];
    __shared__ float sfac[RB];

    const int t    = threadIdx.x;
    const int wv_i = t >> 6;
    const int lane = t & 63;
    const int g    = lane >> 4;
    const int e0   = (lane & 15) << 2;

    const int row0 = blockIdx.x * RB;
    const int srow = t >> 4;
    const int sseg = t & 15;

    const float* xrow = x + (size_t)(row0 + srow) * H;

    float acc[4][4];
#pragma unroll
    for (int a = 0; a < 4; ++a)
#pragma unroll
        for (int b = 0; b < 4; ++b) acc[a][b] = 0.0f;

    float sumsq = 0.0f;
    float4 xv[8];
#pragma unroll
    for (int i = 0; i < 8; ++i)
        xv[i] = *(const float4*)(xrow + sseg * 4 + i * 64);

    for (int c = 0; c < NCH; ++c) {
        const float* pbase = pds + c * CB;
#pragma unroll
        for (int i = 0; i < 8; ++i) {
            const int hl = sseg * 4 + i * 64;
            const float4 a4 = xv[i];
            const float4 p4 = *(const float4*)(pbase + hl);
            sumsq += a4.x * a4.x + a4.y * a4.y + a4.z * a4.z + a4.w * a4.w;
            float4 y4;
            y4.x = a4.x * p4.x; y4.y = a4.y * p4.y;
            y4.z = a4.z * p4.z; y4.w = a4.w * p4.w;
            *(float4*)(&yb[srow * PITCH + hl]) = y4;
        }
        __syncthreads();

        if (c + 1 < NCH) {
            const int h0n = (c + 1) * CB;
#pragma unroll
            for (int i = 0; i < 8; ++i)
                xv[i] = *(const float4*)(xrow + h0n + sseg * 4 + i * 64);
        }

        const int hb = wv_i * 128;
        const float* wbase = Wm + (size_t)(c * CB) * E + e0;
#pragma unroll 2
        for (int s = 0; s < 32; ++s) {
            const int hh = hb + s * 4;
            const float4 w0 = *(const float4*)(wbase + (size_t)(hh + 0) * E);
            const float4 w1 = *(const float4*)(wbase + (size_t)(hh + 1) * E);
            const float4 w2 = *(const float4*)(wbase + (size_t)(hh + 2) * E);
            const float4 w3 = *(const float4*)(wbase + (size_t)(hh + 3) * E);
#pragma unroll
            for (int rr = 0; rr < 4; ++rr) {
                const float4 y4 = *(const float4*)(&yb[(4 * rr + g) * PITCH + hh]);
                acc[rr][0] = fmaf(y4.w, w3.x, fmaf(y4.z, w2.x, fmaf(y4.y, w1.x, fmaf(y4.x, w0.x, acc[rr][0]))));
                acc[rr][1] = fmaf(y4.w, w3.y, fmaf(y4.z, w2.y, fmaf(y4.y, w1.y, fmaf(y4.x, w0.y, acc[rr][1]))));
                acc[rr][2] = fmaf(y4.w, w3.z, fmaf(y4.z, w2.z, fmaf(y4.y, w1.z, fmaf(y4.x, w0.z, acc[rr][2]))));
                acc[rr][3] = fmaf(y4.w, w3.w, fmaf(y4.z, w2.w, fmaf(y4.y, w1.w, fmaf(y4.x, w0.w, acc[rr][3]))));
            }
        }
        __syncthreads();
    }

    ssbuf[t] = sumsq;
    __syncthreads();
    if (t < RB) {
        float tot = 0.0f;
#pragma unroll
        for (int i = 0; i < 16; ++i) tot += ssbuf[t * 16 + i];
        sfac[t] = rsqrtf(tot * (1.0f / (float)H) + 1e-6f) * 0.022097086912079608f;
    }

#pragma unroll
    for (int rr = 0; rr < 4; ++rr) {
        const int r = 4 * rr + g;
        *(float4*)(&yb[((wv_i * RB) + r) * E + e0]) =
            make_float4(acc[rr][0], acc[rr][1], acc[rr][2], acc[rr][3]);
    }
    __syncthreads();

#pragma unroll
    for (int rr = 0; rr < 4; ++rr) {
        const int r = wv_i * 4 + rr;
        float L = yb[(0 * RB + r) * E + lane] + yb[(1 * RB + r) * E + lane]
                + yb[(2 * RB + r) * E + lane] + yb[(3 * RB + r) * E + lane];
        L *= sfac[r];

        float m = L;
#pragma unroll
        for (int off = 32; off >= 1; off >>= 1)
            m = fmaxf(m, __shfl_xor(m, off));
        const float ev = expf(L - m);
        float S = ev;
#pragma unroll
        for (int off = 32; off >= 1; off >>= 1)
            S += __shfl_xor(S, off);
        const float p = ev / S;

        float v1 = p; int i1 = lane;
#pragma unroll
        for (int off = 32; off >= 1; off >>= 1) {
            const float ov = __shfl_xor(v1, off);
            const int   oi = __shfl_xor(i1, off);
            if (ov > v1 || (ov == v1 && oi < i1)) { v1 = ov; i1 = oi; }
        }
        float v2 = (lane == i1) ? -1.0f : p; int i2 = lane;
#pragma unroll
        for (int off = 32; off >= 1; off >>= 1) {
            const float ov = __shfl_xor(v2, off);
            const int   oi = __shfl_xor(i2, off);
            if (ov > v2 || (ov == v2 && oi < i2)) { v2 = ov; i2 = oi; }
        }
        float v3 = (lane == i1 || lane == i2) ? -1.0f : p;
#pragma unroll
        for (int off = 32; off >= 1; off >>= 1)
            v3 = fmaxf(v3, __shfl_xor(v3, off));

        if (lane == 0 && (v2 - v3) < TAU) {
            const int k = atomicAdd(flags, 1);
            flags[1 + k] = row0 + r;
        }

        const float denom = fmaxf(v1 + v2, 1e-9f);
        const float wA = v1 / denom;
        const float wB = v2 / denom;
        const float o  = (lane == i1) ? wA : ((lane == i2) ? wB : 0.0f);
        out[(size_t)(row0 + r) * E + lane] = o;
    }
}

extern "C" void kernel_launch(void* const* d_in, const int* in_sizes, int n_in,
                              void* d_out, int out_size, void* d_ws, size_t ws_size,
                              hipStream_t stream) {
    const float* x   = (const float*)d_in[0];
    const float* pds = (const float*)d_in[1];
    const float* Wm  = (const float*)d_in[2];
    float* out = (float*)d_out;
    int* flags = (int*)d_ws;

    const int T = in_sizes[0] / H;   // 16384

    if (ws_size >= WS_NEEDED) {
        unsigned short* whi = (unsigned short*)((char*)d_ws + WHI_OFF);
        unsigned short* wlo = (unsigned short*)((char*)d_ws + WLO_OFF);
        hipLaunchKernelGGL(prep_w,     dim3(256),    dim3(64),  0, stream, Wm, pds, flags, whi, wlo);
        hipLaunchKernelGGL(router_4t,  dim3(T / MT), dim3(512), 0, stream, x, whi, wlo, out, flags);
        hipLaunchKernelGGL(router_fix, dim3(128),    dim3(256), 0, stream, x, pds, Wm, out, flags);
    } else {
        hipLaunchKernelGGL(zero_cnt,   dim3(1),      dim3(64),  0, stream, flags);
        hipLaunchKernelGGL(router_f32, dim3(T / RB), dim3(256), 0, stream, x, pds, Wm, out, flags);
        hipLaunchKernelGGL(router_fix, dim3(128),    dim3(256), 0, stream, x, pds, Wm, out, flags);
    }
}